// Round 16
// baseline (50.265 us; speedup 1.0000x reference)
//
#include <hip/hip_runtime.h>
#include <hip/hip_bf16.h>

// InvButterflyLayer via MFMA (bf16 in, fp32 accum). B=256, MID=16384, C=16.
// Live cone: level lvl needs t < 2^(8-lvl); lvl0 t<256 -> x[0:8224).
//
// R16: ZERO-BARRIER wave-private rewrite. Blocks = 1 wave (64 thr).
//  A:  wave = (b, i, t-slice w of 64 lvl0-rows). x-slice staged to private
//      LDS, lvl0-3 private ping planes, lvl3 -> S3. 2048 blocks.
//  BC: wave = (n4 subtree, 4 bi). lvl4 A-frags read DIRECTLY from S3
//      (S3 layout == A-format, coalesced). lvl5-8 private planes (half-full
//      tiles: garbage A-rows only feed discarded D-rows). Dense with swapped
//      operands (A=FE^T u-rows, B=feat bi-cols): u-pairs in-lane, recombine
//      via one shfl_xor across the bi lane. 2048 blocks.
// No __syncthreads anywhere; same-wave LDS RAW ordered by compiler waitcnts.

#define OUT_HALF 2097152

typedef __attribute__((ext_vector_type(4))) float f32x4;
typedef __attribute__((ext_vector_type(8))) short s16x8;

extern __shared__ char smb[];

__device__ __forceinline__ uint fsw(uint a) {
    return a ^ ((((a >> 6) ^ (a >> 8)) & 3u) << 4);
}
__device__ __forceinline__ ushort bfr(float f) {
    __hip_bfloat16 h = __float2bfloat16(f);
    union { __hip_bfloat16 h; ushort u; } cv; cv.h = h; return cv.u;
}
__device__ __forceinline__ uint pk(float a, float b) {
    return (uint)bfr(a) | ((uint)bfr(b) << 16);
}

// W_T frag: lane(m=d, kg): k2 = kg*8.. as 4 packed uints  [verified R11/R13]
#define LDFRAG(dst, fb)                                                      \
    {                                                                        \
        const float* s_ = (fb) + m;                                          \
        _Pragma("unroll")                                                    \
        for (int cq_ = 0; cq_ < 4; cq_++) {                                  \
            int c_ = kg * 4 + cq_;                                           \
            (&(dst).x)[cq_] = pk(s_[c_ * 16], s_[256 + c_ * 16]);            \
        }                                                                    \
    }
// pack D (rows kg*4+reg, pairs) into next-level A rows  [verified R13]
#define PACKW(baseoff, r2)                                                              \
    *(uint*)(smb + fsw((uint)((baseoff) + (r2) * 64 + m * 4))) =                        \
        pk(fmaxf(acc.x, 0.f), fmaxf(acc.y, 0.f));                                       \
    *(uint*)(smb + fsw((uint)((baseoff) + ((r2) + 1) * 64 + m * 4))) =                  \
        pk(fmaxf(acc.z, 0.f), fmaxf(acc.w, 0.f));

// ============ Kernel A: lvl0-3, wave-private, no barriers ============
// LDS: X@0[4224] PA@4224[2048] PB@6272[2x1024] PC@8320[4x512] size 11392
__global__ __launch_bounds__(64, 2)
void ibf_A(const float* __restrict__ in_data, const float* __restrict__ mid_dense,
           const float* __restrict__ in_filter, const float* __restrict__ in_bias,
           const float* __restrict__ filters, const float* __restrict__ biases,
           uint* __restrict__ S3)
{
    const int lane = threadIdx.x;
    const int m = lane & 15, kg = lane >> 4;
    const int b = blockIdx.x;
    const int i = blockIdx.y >> 2;
    const int w = blockIdx.y & 3;

    // stage x slice: elements [2048w, 2048w+2080), component i
    {
        const float4* inb = (const float4*)in_data + (size_t)b * 8192 + (size_t)w * 1024;
        const float4* mdb = (const float4*)mid_dense + (size_t)w * 1024;
        for (int ip = lane; ip < 1040; ip += 64) {
            float4 iv = inb[ip], mv = mdb[ip];
            float xa = i ? iv.y * mv.y : iv.x * mv.x;
            float xb = i ? iv.w * mv.w : iv.z * mv.z;
            *(uint*)(smb + fsw((uint)(ip * 4))) = pk(xa, xb);
        }
    }
    // weight frags + biases into registers (scheduler hoists loads)
    s16x8 b0f, b1f;
#pragma unroll
    for (int j = 0; j < 8; j++) {
        b0f[j] = (short)bfr(in_filter[(kg * 8 + j) * 16 + m]);
        b1f[j] = (short)bfr(in_filter[(32 + kg * 8 + j) * 16 + m]);
    }
    float bv0 = in_bias[m];
    uint4 w1[2]; float bv1[2];
#pragma unroll
    for (int n = 0; n < 2; n++) {
        LDFRAG(w1[n], filters + (size_t)n * 512);
        bv1[n] = biases[n * 16 + m];
    }
    uint4 w2[4]; float bv2[4];
#pragma unroll
    for (int n = 0; n < 4; n++) {
        LDFRAG(w2[n], filters + 131072 + (size_t)n * 512);
        bv2[n] = biases[4096 + n * 16 + m];
    }
    uint4 w3[8]; float bv3[8];
#pragma unroll
    for (int n = 0; n < 8; n++) {
        LDFRAG(w3[n], filters + 2 * 131072 + (size_t)n * 512);
        bv3[n] = biases[2 * 4096 + n * 16 + m];
    }

    // lvl0 (K=64, 2 MFMA/tile): X -> PA
#pragma unroll
    for (int tc = 0; tc < 4; tc++) {
        s16x8 a0 = *(const s16x8*)(smb + fsw((uint)((tc * 16 + m) * 64 + kg * 16)));
        s16x8 a1 = *(const s16x8*)(smb + fsw((uint)((tc * 16 + m) * 64 + 64 + kg * 16)));
        f32x4 acc = {bv0, bv0, bv0, bv0};
        acc = __builtin_amdgcn_mfma_f32_16x16x32_bf16(a0, b0f, acc, 0, 0, 0);
        acc = __builtin_amdgcn_mfma_f32_16x16x32_bf16(a1, b1f, acc, 0, 0, 0);
        const int r2 = tc * 8 + kg * 2;
        PACKW(4224, r2);
    }
    // lvl1: PA -> PB (2 planes)
#pragma unroll
    for (int tc = 0; tc < 2; tc++) {
        s16x8 af = *(const s16x8*)(smb + fsw((uint)(4224 + (tc * 16 + m) * 64 + kg * 16)));
#pragma unroll
        for (int s = 0; s < 2; s++) {
            f32x4 acc = {bv1[s], bv1[s], bv1[s], bv1[s]};
            acc = __builtin_amdgcn_mfma_f32_16x16x32_bf16(af, *(const s16x8*)&w1[s], acc, 0, 0, 0);
            const int r2 = tc * 8 + kg * 2;
            PACKW(6272 + s * 1024, r2);
        }
    }
    // lvl2: PB -> PC (4 planes)
#pragma unroll
    for (int p = 0; p < 2; p++) {
        s16x8 af = *(const s16x8*)(smb + fsw((uint)(6272 + p * 1024 + m * 64 + kg * 16)));
#pragma unroll
        for (int s = 0; s < 2; s++) {
            const int nl = 2 * p + s;
            f32x4 acc = {bv2[nl], bv2[nl], bv2[nl], bv2[nl]};
            acc = __builtin_amdgcn_mfma_f32_16x16x32_bf16(af, *(const s16x8*)&w2[nl], acc, 0, 0, 0);
            const int r2 = kg * 2;
            PACKW(8320 + nl * 512, r2);
        }
    }
    // lvl3: PC (8 valid rows/plane; D rows>=8 discarded) -> S3
    const int bi = 2 * b + i;
#pragma unroll
    for (int p = 0; p < 4; p++) {
        s16x8 af = *(const s16x8*)(smb + fsw((uint)(8320 + p * 512 + m * 64 + kg * 16)));
#pragma unroll
        for (int s = 0; s < 2; s++) {
            const int nl = 2 * p + s;   // = n3
            f32x4 acc = {bv3[nl], bv3[nl], bv3[nl], bv3[nl]};
            acc = __builtin_amdgcn_mfma_f32_16x16x32_bf16(af, *(const s16x8*)&w3[nl], acc, 0, 0, 0);
            if (kg < 2) {
                const uint idx = ((uint)(nl * 512 + bi) * 16 + (uint)(4 * w + kg * 2)) * 16 + m;
                S3[idx]      = pk(fmaxf(acc.x, 0.f), fmaxf(acc.y, 0.f));
                S3[idx + 16] = pk(fmaxf(acc.z, 0.f), fmaxf(acc.w, 0.f));
            }
        }
    }
}

// ===== Kernel BC: lvl4-8 + dense + recombine, wave-private, no barriers =====
// LDS: PA@0[2048] PB@2048[2x1024] PC@4096[4x512] PD@6144[8x256]
//      FT@8192[16 n8 x 16 bi x 16c bf16 = 8192]   size 16384
__global__ __launch_bounds__(64, 2)
void ibf_BC(const float* __restrict__ filters, const float* __restrict__ biases,
            const float* __restrict__ fea_dense, const uint* __restrict__ S3,
            float* __restrict__ out)
{
    const int lane = threadIdx.x;
    const int m = lane & 15, kg = lane >> 4;
    const int n3 = blockIdx.x;
    const int c4 = blockIdx.y >> 1;
    const int n4 = 2 * n3 + (blockIdx.y & 1);
    const int bi0 = c4 * 4;

    // weight frags lvl4-7 upfront (registers); lvl8 JIT in-loop
    uint4 f4; float bv4;
    LDFRAG(f4, filters + 3 * 131072 + (size_t)n4 * 512);
    bv4 = biases[3 * 4096 + n4 * 16 + m];
    uint4 f5[2]; float bv5[2];
#pragma unroll
    for (int n = 0; n < 2; n++) {
        LDFRAG(f5[n], filters + 4 * 131072 + (size_t)(2 * n4 + n) * 512);
        bv5[n] = biases[4 * 4096 + (2 * n4 + n) * 16 + m];
    }
    uint4 f6[4]; float bv6[4];
#pragma unroll
    for (int n = 0; n < 4; n++) {
        LDFRAG(f6[n], filters + 5 * 131072 + (size_t)(4 * n4 + n) * 512);
        bv6[n] = biases[5 * 4096 + (4 * n4 + n) * 16 + m];
    }
    uint4 f7[8]; float bv7[8];
#pragma unroll
    for (int n = 0; n < 8; n++) {
        LDFRAG(f7[n], filters + 6 * 131072 + (size_t)(8 * n4 + n) * 512);
        bv7[n] = biases[6 * 4096 + (8 * n4 + n) * 16 + m];
    }

    // lvl4: A-frags DIRECT from S3 (row (bi,t4) = 64B, coalesced) -> PA
#pragma unroll
    for (int tc = 0; tc < 4; tc++) {
        const char* rb = (const char*)S3 + (size_t)(n3 * 512 + bi0 + tc) * 1024;
        s16x8 af = *(const s16x8*)(rb + m * 64 + kg * 16);
        f32x4 acc = {bv4, bv4, bv4, bv4};
        acc = __builtin_amdgcn_mfma_f32_16x16x32_bf16(af, *(const s16x8*)&f4, acc, 0, 0, 0);
        const int r2 = tc * 8 + kg * 2;
        PACKW(0, r2);
    }
    // lvl5: PA -> PB
#pragma unroll
    for (int tc = 0; tc < 2; tc++) {
        s16x8 af = *(const s16x8*)(smb + fsw((uint)((tc * 16 + m) * 64 + kg * 16)));
#pragma unroll
        for (int s = 0; s < 2; s++) {
            f32x4 acc = {bv5[s], bv5[s], bv5[s], bv5[s]};
            acc = __builtin_amdgcn_mfma_f32_16x16x32_bf16(af, *(const s16x8*)&f5[s], acc, 0, 0, 0);
            const int r2 = tc * 8 + kg * 2;
            PACKW(2048 + s * 1024, r2);
        }
    }
    // lvl6: PB -> PC
#pragma unroll
    for (int p = 0; p < 2; p++) {
        s16x8 af = *(const s16x8*)(smb + fsw((uint)(2048 + p * 1024 + m * 64 + kg * 16)));
#pragma unroll
        for (int s = 0; s < 2; s++) {
            const int nl = 2 * p + s;
            f32x4 acc = {bv6[nl], bv6[nl], bv6[nl], bv6[nl]};
            acc = __builtin_amdgcn_mfma_f32_16x16x32_bf16(af, *(const s16x8*)&f6[nl], acc, 0, 0, 0);
            const int r2 = kg * 2;
            PACKW(4096 + nl * 512, r2);
        }
    }
    // lvl7: PC (8 valid rows/plane) -> PD  (valid D rows: kg<2)
#pragma unroll
    for (int p = 0; p < 4; p++) {
        s16x8 af = *(const s16x8*)(smb + fsw((uint)(4096 + p * 512 + m * 64 + kg * 16)));
#pragma unroll
        for (int s = 0; s < 2; s++) {
            const int nl = 2 * p + s;
            f32x4 acc = {bv7[nl], bv7[nl], bv7[nl], bv7[nl]};
            acc = __builtin_amdgcn_mfma_f32_16x16x32_bf16(af, *(const s16x8*)&f7[nl], acc, 0, 0, 0);
            if (kg < 2) {
                const int r2 = kg * 2;
                PACKW(6144 + nl * 256, r2);
            }
        }
    }
    // lvl8: PD (4 valid rows/plane) -> FT[nl][bi][c] bf16  (valid: kg==0)
#pragma unroll
    for (int p = 0; p < 8; p++) {
        s16x8 af = *(const s16x8*)(smb + fsw((uint)(6144 + p * 256 + m * 64 + kg * 16)));
#pragma unroll
        for (int s = 0; s < 2; s++) {
            const int nl = 2 * p + s;
            uint4 f8; LDFRAG(f8, filters + 7 * 131072 + (size_t)(16 * n4 + nl) * 512);
            float bv8 = biases[7 * 4096 + (16 * n4 + nl) * 16 + m];
            f32x4 acc = {bv8, bv8, bv8, bv8};
            acc = __builtin_amdgcn_mfma_f32_16x16x32_bf16(af, *(const s16x8*)&f8, acc, 0, 0, 0);
            if (kg == 0) {
                float v[4] = {fmaxf(acc.x, 0.f), fmaxf(acc.y, 0.f),
                              fmaxf(acc.z, 0.f), fmaxf(acc.w, 0.f)};
#pragma unroll
                for (int j = 0; j < 4; j++)
                    *(ushort*)(smb + 8192 + nl * 512 + j * 32 + m * 2) = bfr(v[j]);
            }
        }
    }
    // dense (swapped): A = FE^T (rows u, lane m = u%16), B = feat (cols bi = m)
    // D: col = bi (lane m), rows = u (kg*4+reg). u-pairs in-lane; I via lane^1.
    const float inv = 1.f / 16384.f;
    const float* feb = fea_dense + (size_t)(n4 * 16) * 1024;
#pragma unroll 2
    for (int nl8 = 0; nl8 < 16; nl8++) {
        s16x8 bf = {0, 0, 0, 0, 0, 0, 0, 0};
        if (kg < 2) bf = *(const s16x8*)(smb + 8192 + nl8 * 512 + m * 32 + kg * 16);
        const float* fp = feb + nl8 * 1024;
        const int gj0 = (n4 * 16 + nl8) * 32;
#pragma unroll
        for (int ut = 0; ut < 4; ut++) {
            s16x8 af = {0, 0, 0, 0, 0, 0, 0, 0};
            if (kg < 2) {
                const float* fa = fp + (kg * 8) * 64 + ut * 16 + m;
#pragma unroll
                for (int j = 0; j < 8; j++) af[j] = (short)bfr(fa[j * 64]);
            }
            f32x4 acc = {0.f, 0.f, 0.f, 0.f};
            acc = __builtin_amdgcn_mfma_f32_16x16x32_bf16(af, bf, acc, 0, 0, 0);
            float sy = __shfl_xor(acc.y, 1);
            float sw = __shfl_xor(acc.w, 1);
            if (((m & 1) == 0) && m < 4) {
                const int b0 = 2 * c4 + (m >> 1);
                const int j = gj0 + ut * 8 + kg * 2;
                *(float2*)(out + (size_t)b0 * 8192 + j) =
                    make_float2((acc.x - sy) * inv, (acc.z - sw) * inv);
                *(float2*)(out + OUT_HALF + (size_t)b0 * 8192 + j) =
                    make_float2(acc.y, acc.w);
            }
        }
    }
}

extern "C" void kernel_launch(void* const* d_in, const int* in_sizes, int n_in,
                              void* d_out, int out_size, void* d_ws, size_t ws_size,
                              hipStream_t stream) {
    const float* in_data   = (const float*)d_in[0];
    const float* mid_dense = (const float*)d_in[1];
    const float* in_filter = (const float*)d_in[2];
    const float* in_bias   = (const float*)d_in[3];
    const float* filters   = (const float*)d_in[4];
    const float* biases    = (const float*)d_in[5];
    const float* fea_dense = (const float*)d_in[6];
    float* out = (float*)d_out;
    uint* S3   = (uint*)d_ws;   // 4 MB

    ibf_A<<<dim3(256, 8), 64, 11392, stream>>>(in_data, mid_dense, in_filter, in_bias,
                                               filters, biases, S3);
    ibf_BC<<<dim3(8, 256), 64, 16384, stream>>>(filters, biases, fea_dense, S3, out);
}

// Round 17
// 43.171 us; speedup vs baseline: 1.1643x; 1.1643x over previous
//
#include <hip/hip_runtime.h>
#include <hip/hip_bf16.h>

// InvButterflyLayer via MFMA (bf16 in, fp32 accum). B=256, MID=16384, C=16.
// Live cone: level lvl needs t < 2^(8-lvl); lvl0 t<256 -> x[0:8224).
//
// R17: zero-barrier wave-private everywhere + NO in-loop global loads
// (R16 lesson: A=1.5us with hoisted weights; BC=48us with 640 in-loop loads).
//  A : unchanged from R16 (lvl0-3 -> S3). 2048 blocks x 64thr.
//  B1: lvl4-8 tree, ALL weight frags hoisted to regs, feat -> S8. 2048x64.
//  C : dense+recombine, FE frags hoisted, S8 B-frags prefetched 1-deep,
//      16 valid bi cols/tile (4x R16's efficiency). 512 blocks x 256thr.

#define OUT_HALF 2097152

typedef __attribute__((ext_vector_type(4))) float f32x4;
typedef __attribute__((ext_vector_type(8))) short s16x8;

extern __shared__ char smb[];

__device__ __forceinline__ uint fsw(uint a) {
    return a ^ ((((a >> 6) ^ (a >> 8)) & 3u) << 4);
}
__device__ __forceinline__ ushort bfr(float f) {
    __hip_bfloat16 h = __float2bfloat16(f);
    union { __hip_bfloat16 h; ushort u; } cv; cv.h = h; return cv.u;
}
__device__ __forceinline__ uint pk(float a, float b) {
    return (uint)bfr(a) | ((uint)bfr(b) << 16);
}

// W_T frag: lane(m=d, kg): k2 = kg*8.. as 4 packed uints  [verified R11-R16]
#define LDFRAG(dst, fb)                                                      \
    {                                                                        \
        const float* s_ = (fb) + m;                                          \
        _Pragma("unroll")                                                    \
        for (int cq_ = 0; cq_ < 4; cq_++) {                                  \
            int c_ = kg * 4 + cq_;                                           \
            (&(dst).x)[cq_] = pk(s_[c_ * 16], s_[256 + c_ * 16]);            \
        }                                                                    \
    }
// pack D (rows kg*4+reg, pairs) into next-level A rows  [verified R13-R16]
#define PACKW(baseoff, r2)                                                              \
    *(uint*)(smb + fsw((uint)((baseoff) + (r2) * 64 + m * 4))) =                        \
        pk(fmaxf(acc.x, 0.f), fmaxf(acc.y, 0.f));                                       \
    *(uint*)(smb + fsw((uint)((baseoff) + ((r2) + 1) * 64 + m * 4))) =                  \
        pk(fmaxf(acc.z, 0.f), fmaxf(acc.w, 0.f));

// ============ Kernel A: lvl0-3, wave-private (identical to R16) ============
// LDS: X@0[4224] PA@4224[2048] PB@6272[2x1024] PC@8320[4x512] size 11392
__global__ __launch_bounds__(64, 2)
void ibf_A(const float* __restrict__ in_data, const float* __restrict__ mid_dense,
           const float* __restrict__ in_filter, const float* __restrict__ in_bias,
           const float* __restrict__ filters, const float* __restrict__ biases,
           uint* __restrict__ S3)
{
    const int lane = threadIdx.x;
    const int m = lane & 15, kg = lane >> 4;
    const int b = blockIdx.x;
    const int i = blockIdx.y >> 2;
    const int w = blockIdx.y & 3;

    {
        const float4* inb = (const float4*)in_data + (size_t)b * 8192 + (size_t)w * 1024;
        const float4* mdb = (const float4*)mid_dense + (size_t)w * 1024;
        for (int ip = lane; ip < 1040; ip += 64) {
            float4 iv = inb[ip], mv = mdb[ip];
            float xa = i ? iv.y * mv.y : iv.x * mv.x;
            float xb = i ? iv.w * mv.w : iv.z * mv.z;
            *(uint*)(smb + fsw((uint)(ip * 4))) = pk(xa, xb);
        }
    }
    s16x8 b0f, b1f;
#pragma unroll
    for (int j = 0; j < 8; j++) {
        b0f[j] = (short)bfr(in_filter[(kg * 8 + j) * 16 + m]);
        b1f[j] = (short)bfr(in_filter[(32 + kg * 8 + j) * 16 + m]);
    }
    float bv0 = in_bias[m];
    uint4 w1[2]; float bv1[2];
#pragma unroll
    for (int n = 0; n < 2; n++) {
        LDFRAG(w1[n], filters + (size_t)n * 512);
        bv1[n] = biases[n * 16 + m];
    }
    uint4 w2[4]; float bv2[4];
#pragma unroll
    for (int n = 0; n < 4; n++) {
        LDFRAG(w2[n], filters + 131072 + (size_t)n * 512);
        bv2[n] = biases[4096 + n * 16 + m];
    }
    uint4 w3[8]; float bv3[8];
#pragma unroll
    for (int n = 0; n < 8; n++) {
        LDFRAG(w3[n], filters + 2 * 131072 + (size_t)n * 512);
        bv3[n] = biases[2 * 4096 + n * 16 + m];
    }

#pragma unroll
    for (int tc = 0; tc < 4; tc++) {
        s16x8 a0 = *(const s16x8*)(smb + fsw((uint)((tc * 16 + m) * 64 + kg * 16)));
        s16x8 a1 = *(const s16x8*)(smb + fsw((uint)((tc * 16 + m) * 64 + 64 + kg * 16)));
        f32x4 acc = {bv0, bv0, bv0, bv0};
        acc = __builtin_amdgcn_mfma_f32_16x16x32_bf16(a0, b0f, acc, 0, 0, 0);
        acc = __builtin_amdgcn_mfma_f32_16x16x32_bf16(a1, b1f, acc, 0, 0, 0);
        const int r2 = tc * 8 + kg * 2;
        PACKW(4224, r2);
    }
#pragma unroll
    for (int tc = 0; tc < 2; tc++) {
        s16x8 af = *(const s16x8*)(smb + fsw((uint)(4224 + (tc * 16 + m) * 64 + kg * 16)));
#pragma unroll
        for (int s = 0; s < 2; s++) {
            f32x4 acc = {bv1[s], bv1[s], bv1[s], bv1[s]};
            acc = __builtin_amdgcn_mfma_f32_16x16x32_bf16(af, *(const s16x8*)&w1[s], acc, 0, 0, 0);
            const int r2 = tc * 8 + kg * 2;
            PACKW(6272 + s * 1024, r2);
        }
    }
#pragma unroll
    for (int p = 0; p < 2; p++) {
        s16x8 af = *(const s16x8*)(smb + fsw((uint)(6272 + p * 1024 + m * 64 + kg * 16)));
#pragma unroll
        for (int s = 0; s < 2; s++) {
            const int nl = 2 * p + s;
            f32x4 acc = {bv2[nl], bv2[nl], bv2[nl], bv2[nl]};
            acc = __builtin_amdgcn_mfma_f32_16x16x32_bf16(af, *(const s16x8*)&w2[nl], acc, 0, 0, 0);
            const int r2 = kg * 2;
            PACKW(8320 + nl * 512, r2);
        }
    }
    const int bi = 2 * b + i;
#pragma unroll
    for (int p = 0; p < 4; p++) {
        s16x8 af = *(const s16x8*)(smb + fsw((uint)(8320 + p * 512 + m * 64 + kg * 16)));
#pragma unroll
        for (int s = 0; s < 2; s++) {
            const int nl = 2 * p + s;
            f32x4 acc = {bv3[nl], bv3[nl], bv3[nl], bv3[nl]};
            acc = __builtin_amdgcn_mfma_f32_16x16x32_bf16(af, *(const s16x8*)&w3[nl], acc, 0, 0, 0);
            if (kg < 2) {
                const uint idx = ((uint)(nl * 512 + bi) * 16 + (uint)(4 * w + kg * 2)) * 16 + m;
                S3[idx]      = pk(fmaxf(acc.x, 0.f), fmaxf(acc.y, 0.f));
                S3[idx + 16] = pk(fmaxf(acc.z, 0.f), fmaxf(acc.w, 0.f));
            }
        }
    }
}

// ===== Kernel B1: lvl4-8 tree, ALL weights hoisted, feat -> S8 =====
// LDS: PA@0[2048] PB@2048[2x1024] PC@4096[4x512] PD@6144[8x256]
//      FT@8192[16 nl x (4 bi x 16c)] size 16384
__global__ __launch_bounds__(64, 2)
void ibf_B1(const float* __restrict__ filters, const float* __restrict__ biases,
            const uint* __restrict__ S3, uint* __restrict__ S8u)
{
    const int lane = threadIdx.x;
    const int m = lane & 15, kg = lane >> 4;
    const int n3 = blockIdx.x;
    const int c4 = blockIdx.y >> 1;
    const int n4 = 2 * n3 + (blockIdx.y & 1);
    const int bi0 = c4 * 4;

    // ---- hoist ALL weight frags + biases (no in-loop global loads) ----
    uint4 f4; float bv4;
    LDFRAG(f4, filters + 3 * 131072 + (size_t)n4 * 512);
    bv4 = biases[3 * 4096 + n4 * 16 + m];
    uint4 f5[2]; float bv5[2];
#pragma unroll
    for (int n = 0; n < 2; n++) {
        LDFRAG(f5[n], filters + 4 * 131072 + (size_t)(2 * n4 + n) * 512);
        bv5[n] = biases[4 * 4096 + (2 * n4 + n) * 16 + m];
    }
    uint4 f6[4]; float bv6[4];
#pragma unroll
    for (int n = 0; n < 4; n++) {
        LDFRAG(f6[n], filters + 5 * 131072 + (size_t)(4 * n4 + n) * 512);
        bv6[n] = biases[5 * 4096 + (4 * n4 + n) * 16 + m];
    }
    uint4 f7[8]; float bv7[8];
#pragma unroll
    for (int n = 0; n < 8; n++) {
        LDFRAG(f7[n], filters + 6 * 131072 + (size_t)(8 * n4 + n) * 512);
        bv7[n] = biases[6 * 4096 + (8 * n4 + n) * 16 + m];
    }
    uint4 f8[16]; float bv8[16];
#pragma unroll
    for (int n = 0; n < 16; n++) {
        LDFRAG(f8[n], filters + 7 * 131072 + (size_t)(16 * n4 + n) * 512);
        bv8[n] = biases[7 * 4096 + (16 * n4 + n) * 16 + m];
    }

    // lvl4: A-frags DIRECT from S3 -> PA
#pragma unroll
    for (int tc = 0; tc < 4; tc++) {
        const char* rb = (const char*)S3 + (size_t)(n3 * 512 + bi0 + tc) * 1024;
        s16x8 af = *(const s16x8*)(rb + m * 64 + kg * 16);
        f32x4 acc = {bv4, bv4, bv4, bv4};
        acc = __builtin_amdgcn_mfma_f32_16x16x32_bf16(af, *(const s16x8*)&f4, acc, 0, 0, 0);
        const int r2 = tc * 8 + kg * 2;
        PACKW(0, r2);
    }
    // lvl5: PA -> PB
#pragma unroll
    for (int tc = 0; tc < 2; tc++) {
        s16x8 af = *(const s16x8*)(smb + fsw((uint)((tc * 16 + m) * 64 + kg * 16)));
#pragma unroll
        for (int s = 0; s < 2; s++) {
            f32x4 acc = {bv5[s], bv5[s], bv5[s], bv5[s]};
            acc = __builtin_amdgcn_mfma_f32_16x16x32_bf16(af, *(const s16x8*)&f5[s], acc, 0, 0, 0);
            const int r2 = tc * 8 + kg * 2;
            PACKW(2048 + s * 1024, r2);
        }
    }
    // lvl6: PB -> PC
#pragma unroll
    for (int p = 0; p < 2; p++) {
        s16x8 af = *(const s16x8*)(smb + fsw((uint)(2048 + p * 1024 + m * 64 + kg * 16)));
#pragma unroll
        for (int s = 0; s < 2; s++) {
            const int nl = 2 * p + s;
            f32x4 acc = {bv6[nl], bv6[nl], bv6[nl], bv6[nl]};
            acc = __builtin_amdgcn_mfma_f32_16x16x32_bf16(af, *(const s16x8*)&f6[nl], acc, 0, 0, 0);
            const int r2 = kg * 2;
            PACKW(4096 + nl * 512, r2);
        }
    }
    // lvl7: PC -> PD (valid D rows kg<2)
#pragma unroll
    for (int p = 0; p < 4; p++) {
        s16x8 af = *(const s16x8*)(smb + fsw((uint)(4096 + p * 512 + m * 64 + kg * 16)));
#pragma unroll
        for (int s = 0; s < 2; s++) {
            const int nl = 2 * p + s;
            f32x4 acc = {bv7[nl], bv7[nl], bv7[nl], bv7[nl]};
            acc = __builtin_amdgcn_mfma_f32_16x16x32_bf16(af, *(const s16x8*)&f7[nl], acc, 0, 0, 0);
            if (kg < 2) {
                const int r2 = kg * 2;
                PACKW(6144 + nl * 256, r2);
            }
        }
    }
    // lvl8: PD -> FT[nl][bi4][c] bf16 (valid rows: kg==0)
#pragma unroll
    for (int p = 0; p < 8; p++) {
        s16x8 af = *(const s16x8*)(smb + fsw((uint)(6144 + p * 256 + m * 64 + kg * 16)));
#pragma unroll
        for (int s = 0; s < 2; s++) {
            const int nl = 2 * p + s;
            f32x4 acc = {bv8[nl], bv8[nl], bv8[nl], bv8[nl]};
            acc = __builtin_amdgcn_mfma_f32_16x16x32_bf16(af, *(const s16x8*)&f8[nl], acc, 0, 0, 0);
            if (kg == 0) {
                float v[4] = {fmaxf(acc.x, 0.f), fmaxf(acc.y, 0.f),
                              fmaxf(acc.z, 0.f), fmaxf(acc.w, 0.f)};
#pragma unroll
                for (int j = 0; j < 4; j++)
                    *(ushort*)(smb + 8192 + nl * 512 + j * 32 + m * 2) = bfr(v[j]);
            }
        }
    }
    // FT -> S8[n8][bi][c] (uint = c-pair), coalesced-ish
    for (int idx = lane; idx < 512; idx += 64) {
        const int nl = idx >> 5, r = idx & 31, j = r >> 3, cp = r & 7;
        uint v = *(const uint*)(smb + 8192 + nl * 512 + j * 32 + cp * 4);
        S8u[((uint)((n4 * 16 + nl) * 512 + bi0 + j)) * 8 + cp] = v;
    }
}

// ===== Kernel C: dense 16->64 + recombine; no LDS, no barriers =====
// A = FE^T (rows u, hoisted), B = feat[bi][c] from S8 (prefetched 1-deep).
// D: col m = bi (16 valid), rows = u_local = kg*4+reg. [math verified R16]
__global__ __launch_bounds__(256, 4)
void ibf_C(const float* __restrict__ fea_dense, const uint* __restrict__ S8u,
           float* __restrict__ out)
{
    const int tid = threadIdx.x, lane = tid & 63, wave = tid >> 6;
    const int m = lane & 15, kg = lane >> 4;
    const int n8 = blockIdx.x;
    const int half = blockIdx.y;
    const float inv = 1.f / 16384.f;

    s16x8 afr[4];
#pragma unroll
    for (int ut = 0; ut < 4; ut++) afr[ut] = (s16x8){0, 0, 0, 0, 0, 0, 0, 0};
    if (kg < 2) {
        const float* fp = fea_dense + (size_t)n8 * 1024 + (size_t)(kg * 8) * 64 + m;
#pragma unroll
        for (int ut = 0; ut < 4; ut++)
#pragma unroll
            for (int j = 0; j < 8; j++)
                afr[ut][j] = (short)bfr(fp[ut * 16 + j * 64]);
    }
    const int gj0 = n8 * 32;
    const int tile0 = half * 16 + wave * 4;

    s16x8 bfc = {0, 0, 0, 0, 0, 0, 0, 0};
    if (kg < 2)
        bfc = *(const s16x8*)((const char*)S8u +
                ((size_t)(n8 * 512 + tile0 * 16 + m)) * 32 + kg * 16);
#pragma unroll
    for (int t = 0; t < 4; t++) {
        const int tile = tile0 + t;
        s16x8 bfn = {0, 0, 0, 0, 0, 0, 0, 0};
        if (t < 3 && kg < 2)
            bfn = *(const s16x8*)((const char*)S8u +
                    ((size_t)(n8 * 512 + (tile + 1) * 16 + m)) * 32 + kg * 16);
        const bool evenm = ((m & 1) == 0);
        const int b0 = (tile * 16 + m) >> 1;
#pragma unroll
        for (int ut = 0; ut < 4; ut++) {
            f32x4 acc = {0.f, 0.f, 0.f, 0.f};
            acc = __builtin_amdgcn_mfma_f32_16x16x32_bf16(afr[ut], bfc, acc, 0, 0, 0);
            float sy = __shfl_xor(acc.y, 1);
            float sw = __shfl_xor(acc.w, 1);
            if (evenm) {
                const int j = gj0 + ut * 8 + kg * 2;
                *(float2*)(out + (size_t)b0 * 8192 + j) =
                    make_float2((acc.x - sy) * inv, (acc.z - sw) * inv);
                *(float2*)(out + OUT_HALF + (size_t)b0 * 8192 + j) =
                    make_float2(acc.y, acc.w);
            }
        }
        bfc = bfn;
    }
}

extern "C" void kernel_launch(void* const* d_in, const int* in_sizes, int n_in,
                              void* d_out, int out_size, void* d_ws, size_t ws_size,
                              hipStream_t stream) {
    const float* in_data   = (const float*)d_in[0];
    const float* mid_dense = (const float*)d_in[1];
    const float* in_filter = (const float*)d_in[2];
    const float* in_bias   = (const float*)d_in[3];
    const float* filters   = (const float*)d_in[4];
    const float* biases    = (const float*)d_in[5];
    const float* fea_dense = (const float*)d_in[6];
    float* out = (float*)d_out;
    uint* S3   = (uint*)d_ws;                        // 4 MB
    uint* S8u  = (uint*)((char*)d_ws + (4 << 20));   // 4 MB

    ibf_A<<<dim3(256, 8), 64, 11392, stream>>>(in_data, mid_dense, in_filter, in_bias,
                                               filters, biases, S3);
    ibf_B1<<<dim3(8, 256), 64, 16384, stream>>>(filters, biases, S3, S8u);
    ibf_C<<<dim3(256, 2), 256, 0, stream>>>(fea_dense, S8u, out);
}

// Round 18
// 35.899 us; speedup vs baseline: 1.4002x; 1.2025x over previous
//
#include <hip/hip_runtime.h>
#include <hip/hip_bf16.h>

// InvButterflyLayer via MFMA (bf16 in, fp32 accum). B=256, MID=16384, C=16.
// Live cone: level lvl needs t < 2^(8-lvl); lvl0 t<256 -> x[0:8224).
//
// R18: zero-barrier wave-private; weight-register pressure split across
// kernels (R17 lesson: hoisting 31 frags = ~190 VGPR at 64thr was the drag).
//  A : unchanged (R16/R17, ~1.5us). lvl0-3 -> S3.
//  B2: lvl4-7 only; hoists f4..f7 (15 frags, 60 VGPR). lvl7 rows -> S7
//      global [n7][bi][k2] (64B rows; byte-mirror of the verified S3 write).
//  C2: per (n8, bi-half): lvl8 (A = contiguous S7 rows, W8 frag hoisted) ->
//      in-wave transpose (512B LDS) -> verified dense+recombine tail.

#define OUT_HALF 2097152

typedef __attribute__((ext_vector_type(4))) float f32x4;
typedef __attribute__((ext_vector_type(8))) short s16x8;

extern __shared__ char smb[];

__device__ __forceinline__ uint fsw(uint a) {
    return a ^ ((((a >> 6) ^ (a >> 8)) & 3u) << 4);
}
__device__ __forceinline__ ushort bfr(float f) {
    __hip_bfloat16 h = __float2bfloat16(f);
    union { __hip_bfloat16 h; ushort u; } cv; cv.h = h; return cv.u;
}
__device__ __forceinline__ uint pk(float a, float b) {
    return (uint)bfr(a) | ((uint)bfr(b) << 16);
}

// W_T frag: lane(m=d, kg): k2 = kg*8.. as 4 packed uints  [verified R11-R17]
#define LDFRAG(dst, fb)                                                      \
    {                                                                        \
        const float* s_ = (fb) + m;                                          \
        _Pragma("unroll")                                                    \
        for (int cq_ = 0; cq_ < 4; cq_++) {                                  \
            int c_ = kg * 4 + cq_;                                           \
            (&(dst).x)[cq_] = pk(s_[c_ * 16], s_[256 + c_ * 16]);            \
        }                                                                    \
    }
// pack D (rows kg*4+reg, pairs) into next-level A rows  [verified R13-R17]
#define PACKW(baseoff, r2)                                                              \
    *(uint*)(smb + fsw((uint)((baseoff) + (r2) * 64 + m * 4))) =                        \
        pk(fmaxf(acc.x, 0.f), fmaxf(acc.y, 0.f));                                       \
    *(uint*)(smb + fsw((uint)((baseoff) + ((r2) + 1) * 64 + m * 4))) =                  \
        pk(fmaxf(acc.z, 0.f), fmaxf(acc.w, 0.f));

// ============ Kernel A: lvl0-3, wave-private (identical to R16/R17) ============
// LDS: X@0[4224] PA@4224[2048] PB@6272[2x1024] PC@8320[4x512] size 11392
__global__ __launch_bounds__(64, 2)
void ibf_A(const float* __restrict__ in_data, const float* __restrict__ mid_dense,
           const float* __restrict__ in_filter, const float* __restrict__ in_bias,
           const float* __restrict__ filters, const float* __restrict__ biases,
           uint* __restrict__ S3)
{
    const int lane = threadIdx.x;
    const int m = lane & 15, kg = lane >> 4;
    const int b = blockIdx.x;
    const int i = blockIdx.y >> 2;
    const int w = blockIdx.y & 3;

    {
        const float4* inb = (const float4*)in_data + (size_t)b * 8192 + (size_t)w * 1024;
        const float4* mdb = (const float4*)mid_dense + (size_t)w * 1024;
        for (int ip = lane; ip < 1040; ip += 64) {
            float4 iv = inb[ip], mv = mdb[ip];
            float xa = i ? iv.y * mv.y : iv.x * mv.x;
            float xb = i ? iv.w * mv.w : iv.z * mv.z;
            *(uint*)(smb + fsw((uint)(ip * 4))) = pk(xa, xb);
        }
    }
    s16x8 b0f, b1f;
#pragma unroll
    for (int j = 0; j < 8; j++) {
        b0f[j] = (short)bfr(in_filter[(kg * 8 + j) * 16 + m]);
        b1f[j] = (short)bfr(in_filter[(32 + kg * 8 + j) * 16 + m]);
    }
    float bv0 = in_bias[m];
    uint4 w1[2]; float bv1[2];
#pragma unroll
    for (int n = 0; n < 2; n++) {
        LDFRAG(w1[n], filters + (size_t)n * 512);
        bv1[n] = biases[n * 16 + m];
    }
    uint4 w2[4]; float bv2[4];
#pragma unroll
    for (int n = 0; n < 4; n++) {
        LDFRAG(w2[n], filters + 131072 + (size_t)n * 512);
        bv2[n] = biases[4096 + n * 16 + m];
    }
    uint4 w3[8]; float bv3[8];
#pragma unroll
    for (int n = 0; n < 8; n++) {
        LDFRAG(w3[n], filters + 2 * 131072 + (size_t)n * 512);
        bv3[n] = biases[2 * 4096 + n * 16 + m];
    }

#pragma unroll
    for (int tc = 0; tc < 4; tc++) {
        s16x8 a0 = *(const s16x8*)(smb + fsw((uint)((tc * 16 + m) * 64 + kg * 16)));
        s16x8 a1 = *(const s16x8*)(smb + fsw((uint)((tc * 16 + m) * 64 + 64 + kg * 16)));
        f32x4 acc = {bv0, bv0, bv0, bv0};
        acc = __builtin_amdgcn_mfma_f32_16x16x32_bf16(a0, b0f, acc, 0, 0, 0);
        acc = __builtin_amdgcn_mfma_f32_16x16x32_bf16(a1, b1f, acc, 0, 0, 0);
        const int r2 = tc * 8 + kg * 2;
        PACKW(4224, r2);
    }
#pragma unroll
    for (int tc = 0; tc < 2; tc++) {
        s16x8 af = *(const s16x8*)(smb + fsw((uint)(4224 + (tc * 16 + m) * 64 + kg * 16)));
#pragma unroll
        for (int s = 0; s < 2; s++) {
            f32x4 acc = {bv1[s], bv1[s], bv1[s], bv1[s]};
            acc = __builtin_amdgcn_mfma_f32_16x16x32_bf16(af, *(const s16x8*)&w1[s], acc, 0, 0, 0);
            const int r2 = tc * 8 + kg * 2;
            PACKW(6272 + s * 1024, r2);
        }
    }
#pragma unroll
    for (int p = 0; p < 2; p++) {
        s16x8 af = *(const s16x8*)(smb + fsw((uint)(6272 + p * 1024 + m * 64 + kg * 16)));
#pragma unroll
        for (int s = 0; s < 2; s++) {
            const int nl = 2 * p + s;
            f32x4 acc = {bv2[nl], bv2[nl], bv2[nl], bv2[nl]};
            acc = __builtin_amdgcn_mfma_f32_16x16x32_bf16(af, *(const s16x8*)&w2[nl], acc, 0, 0, 0);
            const int r2 = kg * 2;
            PACKW(8320 + nl * 512, r2);
        }
    }
    const int bi = 2 * b + i;
#pragma unroll
    for (int p = 0; p < 4; p++) {
        s16x8 af = *(const s16x8*)(smb + fsw((uint)(8320 + p * 512 + m * 64 + kg * 16)));
#pragma unroll
        for (int s = 0; s < 2; s++) {
            const int nl = 2 * p + s;
            f32x4 acc = {bv3[nl], bv3[nl], bv3[nl], bv3[nl]};
            acc = __builtin_amdgcn_mfma_f32_16x16x32_bf16(af, *(const s16x8*)&w3[nl], acc, 0, 0, 0);
            if (kg < 2) {
                const uint idx = ((uint)(nl * 512 + bi) * 16 + (uint)(4 * w + kg * 2)) * 16 + m;
                S3[idx]      = pk(fmaxf(acc.x, 0.f), fmaxf(acc.y, 0.f));
                S3[idx + 16] = pk(fmaxf(acc.z, 0.f), fmaxf(acc.w, 0.f));
            }
        }
    }
}

// ===== Kernel B2: lvl4-7, f4..f7 hoisted (60 VGPR), lvl7 -> S7 global =====
// LDS: PA@0[2048] PB@2048[2x1024] PC@4096[4x512]  size 6144
__global__ __launch_bounds__(64, 2)
void ibf_B2(const float* __restrict__ filters, const float* __restrict__ biases,
            const uint* __restrict__ S3, uint* __restrict__ S7u)
{
    const int lane = threadIdx.x;
    const int m = lane & 15, kg = lane >> 4;
    const int n3 = blockIdx.x;
    const int c4 = blockIdx.y >> 1;
    const int n4 = 2 * n3 + (blockIdx.y & 1);
    const int bi0 = c4 * 4;

    uint4 f4; float bv4;
    LDFRAG(f4, filters + 3 * 131072 + (size_t)n4 * 512);
    bv4 = biases[3 * 4096 + n4 * 16 + m];
    uint4 f5[2]; float bv5[2];
#pragma unroll
    for (int n = 0; n < 2; n++) {
        LDFRAG(f5[n], filters + 4 * 131072 + (size_t)(2 * n4 + n) * 512);
        bv5[n] = biases[4 * 4096 + (2 * n4 + n) * 16 + m];
    }
    uint4 f6[4]; float bv6[4];
#pragma unroll
    for (int n = 0; n < 4; n++) {
        LDFRAG(f6[n], filters + 5 * 131072 + (size_t)(4 * n4 + n) * 512);
        bv6[n] = biases[5 * 4096 + (4 * n4 + n) * 16 + m];
    }
    uint4 f7[8]; float bv7[8];
#pragma unroll
    for (int n = 0; n < 8; n++) {
        LDFRAG(f7[n], filters + 6 * 131072 + (size_t)(8 * n4 + n) * 512);
        bv7[n] = biases[6 * 4096 + (8 * n4 + n) * 16 + m];
    }

    // lvl4: A-frags DIRECT from S3 -> PA
#pragma unroll
    for (int tc = 0; tc < 4; tc++) {
        const char* rb = (const char*)S3 + (size_t)(n3 * 512 + bi0 + tc) * 1024;
        s16x8 af = *(const s16x8*)(rb + m * 64 + kg * 16);
        f32x4 acc = {bv4, bv4, bv4, bv4};
        acc = __builtin_amdgcn_mfma_f32_16x16x32_bf16(af, *(const s16x8*)&f4, acc, 0, 0, 0);
        const int r2 = tc * 8 + kg * 2;
        PACKW(0, r2);
    }
    // lvl5: PA -> PB
#pragma unroll
    for (int tc = 0; tc < 2; tc++) {
        s16x8 af = *(const s16x8*)(smb + fsw((uint)((tc * 16 + m) * 64 + kg * 16)));
#pragma unroll
        for (int s = 0; s < 2; s++) {
            f32x4 acc = {bv5[s], bv5[s], bv5[s], bv5[s]};
            acc = __builtin_amdgcn_mfma_f32_16x16x32_bf16(af, *(const s16x8*)&f5[s], acc, 0, 0, 0);
            const int r2 = tc * 8 + kg * 2;
            PACKW(2048 + s * 1024, r2);
        }
    }
    // lvl6: PB -> PC
#pragma unroll
    for (int p = 0; p < 2; p++) {
        s16x8 af = *(const s16x8*)(smb + fsw((uint)(2048 + p * 1024 + m * 64 + kg * 16)));
#pragma unroll
        for (int s = 0; s < 2; s++) {
            const int nl = 2 * p + s;
            f32x4 acc = {bv6[nl], bv6[nl], bv6[nl], bv6[nl]};
            acc = __builtin_amdgcn_mfma_f32_16x16x32_bf16(af, *(const s16x8*)&f6[nl], acc, 0, 0, 0);
            const int r2 = kg * 2;
            PACKW(4096 + nl * 512, r2);
        }
    }
    // lvl7: PC -> S7 global rows [n7g][bi0+kg*2(+1)] (valid kg<2), 64B rows
#pragma unroll
    for (int p = 0; p < 4; p++) {
        s16x8 af = *(const s16x8*)(smb + fsw((uint)(4096 + p * 512 + m * 64 + kg * 16)));
#pragma unroll
        for (int s = 0; s < 2; s++) {
            const int nl = 2 * p + s;
            f32x4 acc = {bv7[nl], bv7[nl], bv7[nl], bv7[nl]};
            acc = __builtin_amdgcn_mfma_f32_16x16x32_bf16(af, *(const s16x8*)&f7[nl], acc, 0, 0, 0);
            if (kg < 2) {
                const uint n7g = (uint)(8 * n4 + nl);
                const uint idx = ((n7g * 512u + (uint)(bi0 + kg * 2)) * 16u) + (uint)m;
                S7u[idx]      = pk(fmaxf(acc.x, 0.f), fmaxf(acc.y, 0.f));
                S7u[idx + 16] = pk(fmaxf(acc.z, 0.f), fmaxf(acc.w, 0.f));
            }
        }
    }
}

// ===== Kernel C2: lvl8 + dense + recombine, per (n8, bi-half) =====
// A(lvl8) = S7 rows (full K=32); transpose via per-wave 512B LDS; dense tail
// byte-identical to verified R17-C. LDS: 4 waves x 512B = 2048.
__global__ __launch_bounds__(256, 4)
void ibf_C2(const float* __restrict__ fea_dense, const float* __restrict__ filters,
            const float* __restrict__ biases, const uint* __restrict__ S7u,
            float* __restrict__ out)
{
    const int tid = threadIdx.x, lane = tid & 63, wave = tid >> 6;
    const int m = lane & 15, kg = lane >> 4;
    const int n8 = blockIdx.x;
    const int half = blockIdx.y;
    const int n7 = n8 >> 1;
    const float inv = 1.f / 16384.f;
    char* FT = smb + wave * 512;

    // hoists: FE A-frags (dense), W8^T frag, lvl8 bias
    s16x8 afr[4];
#pragma unroll
    for (int ut = 0; ut < 4; ut++) afr[ut] = (s16x8){0, 0, 0, 0, 0, 0, 0, 0};
    if (kg < 2) {
        const float* fp = fea_dense + (size_t)n8 * 1024 + (size_t)(kg * 8) * 64 + m;
#pragma unroll
        for (int ut = 0; ut < 4; ut++)
#pragma unroll
            for (int j = 0; j < 8; j++)
                afr[ut][j] = (short)bfr(fp[ut * 16 + j * 64]);
    }
    uint4 f8;
    LDFRAG(f8, filters + 7 * 131072 + (size_t)n8 * 512);
    const float bv8 = biases[7 * 4096 + n8 * 16 + m];
    const int gj0 = n8 * 32;

    const int tb0 = half * 256 + wave * 64;   // 4 tiles of 16 bi per wave
    // prefetch tile 0's A-frag
    s16x8 a8c = *(const s16x8*)((const char*)S7u +
                   (size_t)(n7 * 512 + tb0 + m) * 64 + kg * 16);
#pragma unroll
    for (int tl = 0; tl < 4; tl++) {
        const int tb = tb0 + tl * 16;
        s16x8 a8n;
        if (tl < 3)
            a8n = *(const s16x8*)((const char*)S7u +
                     (size_t)(n7 * 512 + tb + 16 + m) * 64 + kg * 16);
        // lvl8: D[row=bi_local][col=d] ; relu -> FT[bi][d] (2B scatter)
        {
            f32x4 acc = {bv8, bv8, bv8, bv8};
            acc = __builtin_amdgcn_mfma_f32_16x16x32_bf16(a8c, *(const s16x8*)&f8, acc, 0, 0, 0);
            float v[4] = {fmaxf(acc.x, 0.f), fmaxf(acc.y, 0.f),
                          fmaxf(acc.z, 0.f), fmaxf(acc.w, 0.f)};
#pragma unroll
            for (int j = 0; j < 4; j++)
                *(ushort*)(FT + (kg * 4 + j) * 32 + m * 2) = bfr(v[j]);
        }
        // dense B-frag: feat[bi=m][c=kg*8..], kg<2 (K pad 16..31 = 0)
        s16x8 bf = {0, 0, 0, 0, 0, 0, 0, 0};
        if (kg < 2) bf = *(const s16x8*)(FT + m * 32 + kg * 16);
        const bool evenm = ((m & 1) == 0);
        const int b0 = (tb + m) >> 1;
#pragma unroll
        for (int ut = 0; ut < 4; ut++) {
            f32x4 acc = {0.f, 0.f, 0.f, 0.f};
            acc = __builtin_amdgcn_mfma_f32_16x16x32_bf16(afr[ut], bf, acc, 0, 0, 0);
            float sy = __shfl_xor(acc.y, 1);
            float sw = __shfl_xor(acc.w, 1);
            if (evenm) {
                const int j = gj0 + ut * 8 + kg * 2;
                *(float2*)(out + (size_t)b0 * 8192 + j) =
                    make_float2((acc.x - sy) * inv, (acc.z - sw) * inv);
                *(float2*)(out + OUT_HALF + (size_t)b0 * 8192 + j) =
                    make_float2(acc.y, acc.w);
            }
        }
        a8c = a8n;
    }
}

extern "C" void kernel_launch(void* const* d_in, const int* in_sizes, int n_in,
                              void* d_out, int out_size, void* d_ws, size_t ws_size,
                              hipStream_t stream) {
    const float* in_data   = (const float*)d_in[0];
    const float* mid_dense = (const float*)d_in[1];
    const float* in_filter = (const float*)d_in[2];
    const float* in_bias   = (const float*)d_in[3];
    const float* filters   = (const float*)d_in[4];
    const float* biases    = (const float*)d_in[5];
    const float* fea_dense = (const float*)d_in[6];
    float* out = (float*)d_out;
    uint* S3   = (uint*)d_ws;                        // 4 MB
    uint* S7u  = (uint*)((char*)d_ws + (4 << 20));   // 4 MB

    ibf_A<<<dim3(256, 8), 64, 11392, stream>>>(in_data, mid_dense, in_filter, in_bias,
                                               filters, biases, S3);
    ibf_B2<<<dim3(8, 256), 64, 6144, stream>>>(filters, biases, S3, S7u);
    ibf_C2<<<dim3(256, 2), 256, 2048, stream>>>(fea_dense, filters, biases, S7u, out);
}